// Round 12
// baseline (1415.928 us; speedup 1.0000x reference)
//
#include <hip/hip_runtime.h>
#include <hip/hip_bf16.h>
#include <math.h>

namespace {

constexpr int NB   = 16;     // graphs
constexpr int N1   = 4096;   // points per graph
constexpr int K1   = 1024;   // SA1 centers
constexpr int K2   = 256;    // SA2 centers (== first 256 of SA1 centers)
constexpr int MAXN = 32;     // max neighbors
constexpr int RCAP = 448;    // radius candidate capacity per wave

__device__ __forceinline__ float sigmoidf_(float x) {
  return 1.0f / (1.0f + __expf(-x));
}

__device__ __forceinline__ float readlane_f(float v, int l) {
  return __int_as_float(__builtin_amdgcn_readlane(__float_as_int(v), l));
}

// Packed fp32 FMA (VOP3P, full-rate 2x fp32 on gfx950). Each component is an
// IEEE fma identical to v_fma_f32 -- packing is across INDEPENDENT
// accumulators (row pairs), so results are bit-identical to the scalar form.
__device__ __forceinline__ float2 pk_fma_(float2 a, float2 b, float2 c) {
  float2 d;
  asm("v_pk_fma_f32 %0, %1, %2, %3" : "=v"(d) : "v"(a), "v"(b), "v"(c));
  return d;
}

// ---------------- Farthest-point sampling ----------------
// Measured-best structure: 256 threads / 4 waves, serial per-lane u64-key
// fold, DPP wave reduce, ping-pong LDS cross-wave combine, zero global
// traffic in the loop. Keys: (f32 dist bits << 32) | ~idx so one u64 max =
// "max dist, tie -> smallest index" (jnp.argmax first-occurrence).
// FPS level 2 is eliminated: FPS of an FPS-ordered list = its prefix
// (bitwise, ties included) -> posd2 == posd1[:, :256].

#define FPS_DPP_STEP(CTRL)                                                     \
  {                                                                            \
    const unsigned olo =                                                       \
        (unsigned)__builtin_amdgcn_update_dpp(0, (int)lo, (CTRL), 0xF, 0xF, true); \
    const unsigned ohi =                                                       \
        (unsigned)__builtin_amdgcn_update_dpp(0, (int)hi, (CTRL), 0xF, 0xF, true); \
    const unsigned long long o = ((unsigned long long)ohi << 32) | olo;        \
    const unsigned long long cur = ((unsigned long long)hi << 32) | lo;        \
    if (o > cur) { lo = olo; hi = ohi; }                                       \
  }

template<int NPT>
__device__ __forceinline__ void fps_level(
    const float* __restrict__ sx, const float* __restrict__ sy,
    const float* __restrict__ sz, int k,
    float* __restrict__ selx, float* __restrict__ sely,
    float* __restrict__ selz,                       // LDS, length k
    unsigned long long (*red)[4]) {
  const int t = threadIdx.x;
  const int lane = t & 63, wave = t >> 6;
  float px[NPT], py[NPT], pz[NPT], mind[NPT];
  unsigned niv[NPT];
  const float c0x = sx[0], c0y = sy[0], c0z = sz[0];
  unsigned long long best = 0;  // identity: dist 0, idx ~0 (never wins)
#pragma unroll
  for (int i = 0; i < NPT; i++) {
    const int p = i * 256 + t;
    niv[i] = ~(unsigned)p;
    px[i] = sx[p]; py[i] = sy[p]; pz[i] = sz[p];
    const float dx = px[i] - c0x, dy = py[i] - c0y, dz = pz[i] - c0z;
    const float d2 = dx * dx + dy * dy + dz * dz;
    mind[i] = d2;
    const unsigned long long cand =
        ((unsigned long long)__float_as_uint(d2) << 32) | niv[i];
    if (cand > best) best = cand;
  }
  if (t == 0) { selx[0] = c0x; sely[0] = c0y; selz[0] = c0z; }
  for (int it = 1; it < k; it++) {
    unsigned lo = (unsigned)best, hi = (unsigned)(best >> 32);
    FPS_DPP_STEP(0x111)  // row_shr:1
    FPS_DPP_STEP(0x112)  // row_shr:2
    FPS_DPP_STEP(0x114)  // row_shr:4
    FPS_DPP_STEP(0x118)  // row_shr:8
    FPS_DPP_STEP(0x142)  // row_bcast:15
    FPS_DPP_STEP(0x143)  // row_bcast:31
    const int par = it & 1;
    if (lane == 63) red[par][wave] = ((unsigned long long)hi << 32) | lo;
    __syncthreads();
    const unsigned long long w0 = red[par][0], w1 = red[par][1];
    const unsigned long long w2 = red[par][2], w3 = red[par][3];
    const unsigned long long m01 = w0 > w1 ? w0 : w1;
    const unsigned long long m23 = w2 > w3 ? w2 : w3;
    const unsigned long long win = m01 > m23 ? m01 : m23;
    const int p = (int)(~(unsigned)win);
    const float nx = sx[p], ny = sy[p], nz = sz[p];
    if (t == 0) { selx[it] = nx; sely[it] = ny; selz[it] = nz; }
    best = 0;
#pragma unroll
    for (int i = 0; i < NPT; i++) {
      const float dx = px[i] - nx, dy = py[i] - ny, dz = pz[i] - nz;
      const float d2 = dx * dx + dy * dy + dz * dz;
      const float m = fminf(mind[i], d2);
      mind[i] = m;
      const unsigned long long cand =
          ((unsigned long long)__float_as_uint(m) << 32) | niv[i];
      if (cand > best) best = cand;
    }
  }
}

#undef FPS_DPP_STEP

// ---------------- FPS (4096 -> 1024), one block per graph ----------
__global__ __launch_bounds__(256) void fps_l1_kernel(
    const float* __restrict__ pos, float* __restrict__ posd1,
    unsigned int* __restrict__ gout) {
  __shared__ float sx[N1], sy[N1], sz[N1];       // 48 KiB
  __shared__ float s2x[K1], s2y[K1], s2z[K1];    // 12 KiB (selections)
  __shared__ __align__(16) unsigned long long red[2][4];
  const int b = blockIdx.x;
  const int t = threadIdx.x;
  // zero-init the global-SA atomicMax buffer (replaces a memset launch)
  gout[b * 512 + t] = 0u;
  gout[b * 512 + t + 256] = 0u;
  const float* pb = pos + (size_t)b * N1 * 3;
  for (int p = t; p < N1; p += 256) {
    sx[p] = pb[p * 3 + 0]; sy[p] = pb[p * 3 + 1]; sz[p] = pb[p * 3 + 2];
  }
  __syncthreads();
  fps_level<N1 / 256>(sx, sy, sz, K1, s2x, s2y, s2z, red);
  __syncthreads();
  float* o1 = posd1 + (size_t)b * K1 * 3;
  for (int i = t; i < K1; i += 256) {
    o1[i * 3 + 0] = s2x[i]; o1[i * 3 + 1] = s2y[i]; o1[i * 3 + 2] = s2z[i];
  }
}

// ---------------- radius + 32 nearest ----------------
struct RadSmem {
  float candd[4][RCAP];
  int   candi[4][RCAP];
};

// ctr row index = b*CSTR + ci (CSTR lets centers be a prefix of posd1).
template<int N>
__device__ __forceinline__ void radius_body(
    const float* __restrict__ pts, const float* __restrict__ ctr,
    int K, int CSTR, float r2, int* __restrict__ nbr,
    int* __restrict__ cnt_out, RadSmem& sm, int rb) {
  const int t = threadIdx.x;
  const int lane = t & 63, wave = t >> 6;
  const int bpg = K / 4;
  const int b = rb / bpg;
  const int ci = (rb % bpg) * 4 + wave;
  const float* pb = pts + (size_t)b * N * 3;
  const size_t cbase = ((size_t)b * CSTR + ci) * 3;
  const float cx = ctr[cbase + 0], cy = ctr[cbase + 1], cz = ctr[cbase + 2];
  int total = 0;
  for (int base = 0; base < N; base += 64) {
    const int p = base + lane;
    const float dx = pb[p * 3 + 0] - cx;
    const float dy = pb[p * 3 + 1] - cy;
    const float dz = pb[p * 3 + 2] - cz;
    const float d2 = dx * dx + dy * dy + dz * dz;
    const bool pred = d2 <= r2;
    const unsigned long long m = __ballot(pred);
    if (pred) {
      const int slot = total + __popcll(m & ((1ull << lane) - 1ull));
      if (slot < RCAP) { sm.candd[wave][slot] = d2; sm.candi[wave][slot] = p; }
    }
    total += __popcll(m);
  }
  if (total > RCAP) total = RCAP;
  int* nbp = nbr + ((size_t)b * K + ci) * MAXN;
  if (total <= MAXN) {
    if (lane < total) nbp[lane] = sm.candi[wave][lane];
  } else {
    for (int jj = 0; jj < MAXN; jj++) {
      float bvd = INFINITY; int bvi = 0x7fffffff; int bslot = 0;
      for (int s = lane; s < total; s += 64) {
        const float d = sm.candd[wave][s];
        const int i = sm.candi[wave][s];
        if (d < bvd || (d == bvd && i < bvi)) { bvd = d; bvi = i; bslot = s; }
      }
#pragma unroll
      for (int off = 32; off; off >>= 1) {
        const float od = __shfl_xor(bvd, off);
        const int   oi = __shfl_xor(bvi, off);
        const int   os = __shfl_xor(bslot, off);
        if (od < bvd || (od == bvd && oi < bvi)) { bvd = od; bvi = oi; bslot = os; }
      }
      if (lane == 0) { nbp[jj] = bvi; sm.candd[wave][bslot] = INFINITY; }
    }
  }
  if (lane == 0) cnt_out[(size_t)b * K + ci] = (total < MAXN) ? total : MAXN;
}

// merged radius1 (blocks 0..NB*K1/4-1) | radius2 (rest) — both need only posd1
__global__ __launch_bounds__(256) void rad12_kernel(
    const float* __restrict__ pos, const float* __restrict__ posd1,
    int* __restrict__ nbr1, int* __restrict__ cnt1,
    int* __restrict__ nbr2, int* __restrict__ cnt2) {
  constexpr int NR1 = NB * K1 / 4;
  __shared__ __align__(16) RadSmem r;
  if (blockIdx.x < (unsigned)NR1) {
    radius_body<N1>(pos, posd1, K1, K1, 4.0f, nbr1, cnt1, r, blockIdx.x);
  } else {
    radius_body<K1>(posd1, posd1, K2, K1, 16.0f, nbr2, cnt2, r,
                    blockIdx.x - NR1);
  }
}

// ---------------- PointNetConv edge MLP + max aggregation ----------------
// Rows-in-lanes + readlane broadcast; vectorized weight streaming; packed
// fp32 FMA across row-pairs: the two readlane results fill a float2's halves,
// weights duplicate {w,w} once per output reg. Accumulators per (row, chan)
// are unchanged and combined in the same ascending order -> bit-exact.
template<int CIN_T, int H, int COUT, bool SCALE>
__device__ __forceinline__ void sa_conv_body(
    const float* __restrict__ xin, const float* __restrict__ pts,
    const float* __restrict__ ctr, const int* __restrict__ nbr,
    const int* __restrict__ cnt,
    const float* __restrict__ w1, const float* __restrict__ b1,
    const float* __restrict__ w2, const float* __restrict__ b2,
    const float* __restrict__ smean, const float* __restrict__ sstd,
    int N, int K, int CSTR, float* __restrict__ xout,
    float* part /* LDS [4*COUT] */, int bk) {
  constexpr int FIN  = CIN_T + 3;
  constexpr int KREG = (FIN + 63) / 64;   // feat regs per row per lane
  constexpr int HREG = H / 64;            // hidden regs: h = lane*HREG + q
  constexpr int CREG = COUT / 64;         // out regs:    c = lane*CREG + q
  constexpr int RPW  = MAXN / 4;          // 8 rows per wave
  constexpr int RP2  = RPW / 2;           // row pairs
  const int t = threadIdx.x, lane = t & 63, wave = t >> 6;
  const int b = bk / K;
  const int V = cnt[bk];
  float m[CREG];
#pragma unroll
  for (int ck = 0; ck < CREG; ck++) m[ck] = -INFINITY;
  if (V > wave * RPW) {  // wave-uniform: skip waves with no valid rows
    const int* nb = nbr + (size_t)bk * MAXN;
    const size_t crow = (size_t)b * CSTR + (bk - b * K);
    const float ctrx = ctr[crow * 3 + 0];
    const float ctry = ctr[crow * 3 + 1];
    const float ctrz = ctr[crow * 3 + 2];
    float sm = 0.0f, sd = 1.0f;
    if (SCALE && lane < CIN_T) { sm = smean[lane]; sd = sstd[lane]; }
    float fr[RPW][KREG];
#pragma unroll
    for (int r = 0; r < RPW; r++) {
      const int j = wave * RPW + r;
      const int p = (j < V) ? nb[j] : nb[0];
#pragma unroll
      for (int k2 = 0; k2 < KREG; k2++) {
        const int f = k2 * 64 + lane;
        float v = 0.0f;
        if (f < CIN_T) {
          v = xin[((size_t)b * N + p) * CIN_T + f];
          if constexpr (SCALE) v = (v - sm) / sd;
        } else if (f < FIN) {
          const int d = f - CIN_T;
          const float pv = pts[((size_t)b * N + p) * 3 + d];
          v = pv - (d == 0 ? ctrx : (d == 1 ? ctry : ctrz));
        }
        fr[r][k2] = v;
      }
    }
    // ---- layer 1 (row-pair packed) ----
    float hh[RPW][HREG];
    {
      float2 accv[RP2][HREG];
#pragma unroll
      for (int rp = 0; rp < RP2; rp++)
#pragma unroll
        for (int q = 0; q < HREG; q++) accv[rp][q] = {0.0f, 0.0f};
#pragma unroll
      for (int k2 = 0; k2 < KREG; k2++) {
        const int lim = (FIN - k2 * 64) < 64 ? (FIN - k2 * 64) : 64;
        for (int fl = 0; fl < lim; fl++) {     // f ascending
          const int f = k2 * 64 + fl;
          float2 wv2[HREG];
          if constexpr (HREG == 1) {
            const float w = w1[(size_t)f * H + lane];
            wv2[0] = {w, w};
          } else {
            const float2 w = *reinterpret_cast<const float2*>(
                &w1[(size_t)f * H + lane * 2]);
            wv2[0] = {w.x, w.x}; wv2[1] = {w.y, w.y};
          }
#pragma unroll
          for (int rp = 0; rp < RP2; rp++) {
            float2 sv;
            sv.x = readlane_f(fr[2 * rp + 0][k2], fl);
            sv.y = readlane_f(fr[2 * rp + 1][k2], fl);
#pragma unroll
            for (int q = 0; q < HREG; q++)
              accv[rp][q] = pk_fma_(sv, wv2[q], accv[rp][q]);
          }
        }
      }
#pragma unroll
      for (int q = 0; q < HREG; q++) {
        const float bb = b1[lane * HREG + q];
#pragma unroll
        for (int rp = 0; rp < RP2; rp++) {
          hh[2 * rp + 0][q] = sigmoidf_(accv[rp][q].x + bb);
          hh[2 * rp + 1][q] = sigmoidf_(accv[rp][q].y + bb);
        }
      }
    }
    // ---- layer 2 (h = hl*HREG + q1 ascending; row-pair packed) ----
    float2 acc2v[RP2][CREG];
#pragma unroll
    for (int rp = 0; rp < RP2; rp++)
#pragma unroll
      for (int q = 0; q < CREG; q++) acc2v[rp][q] = {0.0f, 0.0f};
    for (int hl = 0; hl < 64; hl++) {
#pragma unroll
      for (int q1 = 0; q1 < HREG; q1++) {
        const int h = hl * HREG + q1;
        float2 wv2[CREG];
        if constexpr (CREG == 2) {
          const float2 w = *reinterpret_cast<const float2*>(
              &w2[(size_t)h * COUT + lane * 2]);
          wv2[0] = {w.x, w.x}; wv2[1] = {w.y, w.y};
        } else {
          const float4 w = *reinterpret_cast<const float4*>(
              &w2[(size_t)h * COUT + lane * 4]);
          wv2[0] = {w.x, w.x}; wv2[1] = {w.y, w.y};
          wv2[2] = {w.z, w.z}; wv2[3] = {w.w, w.w};
        }
#pragma unroll
        for (int rp = 0; rp < RP2; rp++) {
          float2 sv;
          sv.x = readlane_f(hh[2 * rp + 0][q1], hl);
          sv.y = readlane_f(hh[2 * rp + 1][q1], hl);
#pragma unroll
          for (int q = 0; q < CREG; q++)
            acc2v[rp][q] = pk_fma_(sv, wv2[q], acc2v[rp][q]);
        }
      }
    }
    // ---- masked max over rows (ascending r order, bit-exact) ----
#pragma unroll
    for (int rp = 0; rp < RP2; rp++) {
      if (wave * RPW + 2 * rp + 0 < V) {
#pragma unroll
        for (int q = 0; q < CREG; q++) m[q] = fmaxf(m[q], acc2v[rp][q].x);
      }
      if (wave * RPW + 2 * rp + 1 < V) {
#pragma unroll
        for (int q = 0; q < CREG; q++) m[q] = fmaxf(m[q], acc2v[rp][q].y);
      }
    }
  }
#pragma unroll
  for (int q = 0; q < CREG; q++) part[wave * COUT + lane * CREG + q] = m[q];
  __syncthreads();
  if (t < COUT) {
    const float mm = fmaxf(fmaxf(part[0 * COUT + t], part[1 * COUT + t]),
                           fmaxf(part[2 * COUT + t], part[3 * COUT + t]));
    const float o = mm + b2[t];
    xout[(size_t)bk * COUT + t] = o > 0.0f ? o : 0.0f;
  }
}

__global__ __launch_bounds__(256) void conv1_kernel(
    const float* __restrict__ x, const float* __restrict__ pos,
    const float* __restrict__ posd1, const int* __restrict__ nbr1,
    const int* __restrict__ cnt1,
    const float* __restrict__ s1w1, const float* __restrict__ s1b1,
    const float* __restrict__ s1w2, const float* __restrict__ s1b2,
    const float* __restrict__ smean, const float* __restrict__ sstd,
    float* __restrict__ x1) {
  __shared__ __align__(16) float part[4 * 128];
  sa_conv_body<32, 64, 128, true>(x, pos, posd1, nbr1, cnt1,
                                  s1w1, s1b1, s1w2, s1b2, smean, sstd,
                                  N1, K1, K1, x1, part, blockIdx.x);
}

__global__ __launch_bounds__(256) void conv2_kernel(
    const float* __restrict__ x1, const float* __restrict__ posd1,
    const int* __restrict__ nbr2, const int* __restrict__ cnt2,
    const float* __restrict__ s2w1, const float* __restrict__ s2b1,
    const float* __restrict__ s2w2, const float* __restrict__ s2b2,
    float* __restrict__ x2) {
  __shared__ __align__(16) float part[4 * 256];
  // centers = posd1 prefix rows (stride K1)
  sa_conv_body<128, 128, 256, false>(x1, posd1, posd1, nbr2, cnt2,
                                     s2w1, s2b1, s2w2, s2b2, nullptr, nullptr,
                                     K1, K2, K1, x2, part, blockIdx.x);
}

// ---------------- Global SA: MLP(259->256->512) + relu + max pool ----------
__global__ __launch_bounds__(256) void global_sa_kernel(
    const float* __restrict__ x2, const float* __restrict__ posd1,
    const float* __restrict__ gw1, const float* __restrict__ gb1,
    const float* __restrict__ gw2, const float* __restrict__ gb2,
    unsigned int* __restrict__ gout) {  // [B][512] as float bits (relu >= 0)
  __shared__ float fin[4][259];
  __shared__ float s[4][256];
  const int t = threadIdx.x;
  const int blk = blockIdx.x;
  const int b = blk / 64;
  const int p0 = (blk % 64) * 4;
  for (int item = t; item < 4 * 259; item += 256) {
    const int p = item / 259, f = item - p * 259;
    const float v = (f < 256)
        ? x2[((size_t)b * 256 + p0 + p) * 256 + f]
        : posd1[((size_t)b * K1 + p0 + p) * 3 + (f - 256)];  // posd2 = prefix
    fin[p][f] = v;
  }
  __syncthreads();
  float acc[4] = {0.f, 0.f, 0.f, 0.f};
  for (int f = 0; f < 259; f++) {
    const float w = gw1[f * 256 + t];
#pragma unroll
    for (int p = 0; p < 4; p++) acc[p] = fmaf(fin[p][f], w, acc[p]);
  }
  const float bb = gb1[t];
#pragma unroll
  for (int p = 0; p < 4; p++) s[p][t] = sigmoidf_(acc[p] + bb);
  __syncthreads();
  float a0[4] = {0.f, 0.f, 0.f, 0.f}, a1[4] = {0.f, 0.f, 0.f, 0.f};
  for (int h = 0; h < 256; h++) {
    const float w0 = gw2[h * 512 + t];
    const float w1v = gw2[h * 512 + t + 256];
#pragma unroll
    for (int p = 0; p < 4; p++) {
      a0[p] = fmaf(s[p][h], w0, a0[p]);
      a1[p] = fmaf(s[p][h], w1v, a1[p]);
    }
  }
  const float b0 = gb2[t], b1v = gb2[t + 256];
  float m0 = 0.0f, m1 = 0.0f;  // relu floor
#pragma unroll
  for (int p = 0; p < 4; p++) {
    m0 = fmaxf(m0, fmaxf(a0[p] + b0, 0.0f));
    m1 = fmaxf(m1, fmaxf(a1[p] + b1v, 0.0f));
  }
  atomicMax(&gout[b * 512 + t], __float_as_uint(m0));
  atomicMax(&gout[b * 512 + t + 256], __float_as_uint(m1));
}

// ---------------- Final FC head (float32 output) ----------------
__global__ __launch_bounds__(256) void fc_kernel(
    const unsigned int* __restrict__ g,
    const float* __restrict__ fw1, const float* __restrict__ fb1,
    const float* __restrict__ fw2, const float* __restrict__ fb2,
    float* __restrict__ out) {
  __shared__ float gv[512];
  __shared__ float s[256];
  const int b = blockIdx.x, t = threadIdx.x;
  gv[t] = __uint_as_float(g[b * 512 + t]);
  gv[t + 256] = __uint_as_float(g[b * 512 + t + 256]);
  __syncthreads();
  float acc = 0.0f;
  for (int h = 0; h < 512; h++) acc = fmaf(gv[h], fw1[h * 256 + t], acc);
  s[t] = sigmoidf_(acc + fb1[t]);
  __syncthreads();
  if (t < 128) {
    float a2 = 0.0f;
    for (int h = 0; h < 256; h++) a2 = fmaf(s[h], fw2[h * 128 + t], a2);
    const float o = a2 + fb2[t];
    out[b * 128 + t] = o > 0.0f ? o : 0.0f;
  }
}

}  // namespace

extern "C" void kernel_launch(void* const* d_in, const int* in_sizes, int n_in,
                              void* d_out, int out_size, void* d_ws, size_t ws_size,
                              hipStream_t stream) {
  (void)in_sizes; (void)n_in; (void)out_size; (void)ws_size;
  const float* x     = (const float*)d_in[0];
  const float* pos   = (const float*)d_in[1];
  // d_in[2] = batch (int64) — sorted, equal-sized graphs, unused
  const float* smean = (const float*)d_in[3];
  const float* sstd  = (const float*)d_in[4];
  const float* s1w1  = (const float*)d_in[5];
  const float* s1b1  = (const float*)d_in[6];
  const float* s1w2  = (const float*)d_in[7];
  const float* s1b2  = (const float*)d_in[8];
  const float* s2w1  = (const float*)d_in[9];
  const float* s2b1  = (const float*)d_in[10];
  const float* s2w2  = (const float*)d_in[11];
  const float* s2b2  = (const float*)d_in[12];
  const float* gw1   = (const float*)d_in[13];
  const float* gb1   = (const float*)d_in[14];
  const float* gw2   = (const float*)d_in[15];
  const float* gb2   = (const float*)d_in[16];
  const float* fw1   = (const float*)d_in[17];
  const float* fb1   = (const float*)d_in[18];
  const float* fw2   = (const float*)d_in[19];
  const float* fb2   = (const float*)d_in[20];

  char* ws = (char*)d_ws;
  size_t off = 0;
  auto take = [&](size_t bytes) -> char* {
    char* p = ws + off;
    off = (off + bytes + 255) & ~(size_t)255;
    return p;
  };
  float* posd1       = (float*)take((size_t)NB * K1 * 3 * 4);
  int*   nbr1        = (int*)take((size_t)NB * K1 * MAXN * 4);
  int*   cnt1        = (int*)take((size_t)NB * K1 * 4);
  float* x1          = (float*)take((size_t)NB * K1 * 128 * 4);
  int*   nbr2        = (int*)take((size_t)NB * K2 * MAXN * 4);
  int*   cnt2        = (int*)take((size_t)NB * K2 * 4);
  float* x2          = (float*)take((size_t)NB * K2 * 256 * 4);
  unsigned int* gbuf = (unsigned int*)take((size_t)NB * 512 * 4);

  hipLaunchKernelGGL(fps_l1_kernel, dim3(NB), dim3(256), 0, stream,
                     pos, posd1, gbuf);
  hipLaunchKernelGGL(rad12_kernel, dim3(NB * K1 / 4 + NB * K2 / 4), dim3(256), 0, stream,
                     pos, posd1, nbr1, cnt1, nbr2, cnt2);
  hipLaunchKernelGGL(conv1_kernel, dim3(NB * K1), dim3(256), 0, stream,
                     x, pos, posd1, nbr1, cnt1,
                     s1w1, s1b1, s1w2, s1b2, smean, sstd, x1);
  hipLaunchKernelGGL(conv2_kernel, dim3(NB * K2), dim3(256), 0, stream,
                     x1, posd1, nbr2, cnt2, s2w1, s2b1, s2w2, s2b2, x2);
  hipLaunchKernelGGL(global_sa_kernel, dim3(NB * 64), dim3(256), 0, stream,
                     x2, posd1, gw1, gb1, gw2, gb2, gbuf);
  hipLaunchKernelGGL(fc_kernel, dim3(NB), dim3(256), 0, stream,
                     gbuf, fw1, fb1, fw2, fb2, (float*)d_out);
}

// Round 13
// 1149.372 us; speedup vs baseline: 1.2319x; 1.2319x over previous
//
#include <hip/hip_runtime.h>
#include <hip/hip_bf16.h>
#include <math.h>

namespace {

constexpr int NB   = 16;     // graphs
constexpr int N1   = 4096;   // points per graph
constexpr int K1   = 1024;   // SA1 centers
constexpr int K2   = 256;    // SA2 centers (== first 256 of SA1 centers)
constexpr int MAXN = 32;     // max neighbors
constexpr int RCAP = 448;    // radius candidate capacity per wave

__device__ __forceinline__ float sigmoidf_(float x) {
  return 1.0f / (1.0f + __expf(-x));
}

__device__ __forceinline__ float readlane_f(float v, int l) {
  return __int_as_float(__builtin_amdgcn_readlane(__float_as_int(v), l));
}

// ---------------- Farthest-point sampling ----------------
// Measured-best structure: 256 threads / 4 waves, serial per-lane u64-key
// fold, DPP wave reduce, ping-pong LDS cross-wave combine, zero global
// traffic in the loop. Keys: (f32 dist bits << 32) | ~idx so one u64 max =
// "max dist, tie -> smallest index" (jnp.argmax first-occurrence).
// FPS level 2 eliminated (FPS of an FPS-ordered list = its prefix, bitwise).

#define FPS_DPP_STEP(CTRL)                                                     \
  {                                                                            \
    const unsigned olo =                                                       \
        (unsigned)__builtin_amdgcn_update_dpp(0, (int)lo, (CTRL), 0xF, 0xF, true); \
    const unsigned ohi =                                                       \
        (unsigned)__builtin_amdgcn_update_dpp(0, (int)hi, (CTRL), 0xF, 0xF, true); \
    const unsigned long long o = ((unsigned long long)ohi << 32) | olo;        \
    const unsigned long long cur = ((unsigned long long)hi << 32) | lo;        \
    if (o > cur) { lo = olo; hi = ohi; }                                       \
  }

template<int NPT>
__device__ __forceinline__ void fps_level(
    const float* __restrict__ sx, const float* __restrict__ sy,
    const float* __restrict__ sz, int k,
    float* __restrict__ selx, float* __restrict__ sely,
    float* __restrict__ selz,                       // LDS, length k
    unsigned long long (*red)[4]) {
  const int t = threadIdx.x;
  const int lane = t & 63, wave = t >> 6;
  float px[NPT], py[NPT], pz[NPT], mind[NPT];
  unsigned niv[NPT];
  const float c0x = sx[0], c0y = sy[0], c0z = sz[0];
  unsigned long long best = 0;  // identity: dist 0, idx ~0 (never wins)
#pragma unroll
  for (int i = 0; i < NPT; i++) {
    const int p = i * 256 + t;
    niv[i] = ~(unsigned)p;
    px[i] = sx[p]; py[i] = sy[p]; pz[i] = sz[p];
    const float dx = px[i] - c0x, dy = py[i] - c0y, dz = pz[i] - c0z;
    const float d2 = dx * dx + dy * dy + dz * dz;
    mind[i] = d2;
    const unsigned long long cand =
        ((unsigned long long)__float_as_uint(d2) << 32) | niv[i];
    if (cand > best) best = cand;
  }
  if (t == 0) { selx[0] = c0x; sely[0] = c0y; selz[0] = c0z; }
  for (int it = 1; it < k; it++) {
    unsigned lo = (unsigned)best, hi = (unsigned)(best >> 32);
    FPS_DPP_STEP(0x111)  // row_shr:1
    FPS_DPP_STEP(0x112)  // row_shr:2
    FPS_DPP_STEP(0x114)  // row_shr:4
    FPS_DPP_STEP(0x118)  // row_shr:8
    FPS_DPP_STEP(0x142)  // row_bcast:15
    FPS_DPP_STEP(0x143)  // row_bcast:31
    const int par = it & 1;
    if (lane == 63) red[par][wave] = ((unsigned long long)hi << 32) | lo;
    __syncthreads();
    const unsigned long long w0 = red[par][0], w1 = red[par][1];
    const unsigned long long w2 = red[par][2], w3 = red[par][3];
    const unsigned long long m01 = w0 > w1 ? w0 : w1;
    const unsigned long long m23 = w2 > w3 ? w2 : w3;
    const unsigned long long win = m01 > m23 ? m01 : m23;
    const int p = (int)(~(unsigned)win);
    const float nx = sx[p], ny = sy[p], nz = sz[p];
    if (t == 0) { selx[it] = nx; sely[it] = ny; selz[it] = nz; }
    best = 0;
#pragma unroll
    for (int i = 0; i < NPT; i++) {
      const float dx = px[i] - nx, dy = py[i] - ny, dz = pz[i] - nz;
      const float d2 = dx * dx + dy * dy + dz * dz;
      const float m = fminf(mind[i], d2);
      mind[i] = m;
      const unsigned long long cand =
          ((unsigned long long)__float_as_uint(m) << 32) | niv[i];
      if (cand > best) best = cand;
    }
  }
}

#undef FPS_DPP_STEP

// ---------------- FPS (4096 -> 1024) + SoA emission, one block/graph -------
__global__ __launch_bounds__(256) void fps_l1_kernel(
    const float* __restrict__ pos,
    float* __restrict__ pxg, float* __restrict__ pyg, float* __restrict__ pzg,
    float* __restrict__ d1x, float* __restrict__ d1y, float* __restrict__ d1z,
    unsigned int* __restrict__ gout) {
  __shared__ float sx[N1], sy[N1], sz[N1];       // 48 KiB
  __shared__ float s2x[K1], s2y[K1], s2z[K1];    // 12 KiB (selections)
  __shared__ __align__(16) unsigned long long red[2][4];
  const int b = blockIdx.x;
  const int t = threadIdx.x;
  // zero-init the global-SA atomicMax buffer (replaces a memset launch)
  gout[b * 512 + t] = 0u;
  gout[b * 512 + t + 256] = 0u;
  const float* pb = pos + (size_t)b * N1 * 3;
  for (int p = t; p < N1; p += 256) {
    sx[p] = pb[p * 3 + 0]; sy[p] = pb[p * 3 + 1]; sz[p] = pb[p * 3 + 2];
  }
  __syncthreads();
  fps_level<N1 / 256>(sx, sy, sz, K1, s2x, s2y, s2z, red);
  __syncthreads();
  // SoA copy of all positions (coalesced) for the radius/conv consumers
  for (int p = t; p < N1; p += 256) {
    pxg[(size_t)b * N1 + p] = sx[p];
    pyg[(size_t)b * N1 + p] = sy[p];
    pzg[(size_t)b * N1 + p] = sz[p];
  }
  // SoA center list (coalesced)
  for (int i = t; i < K1; i += 256) {
    d1x[(size_t)b * K1 + i] = s2x[i];
    d1y[(size_t)b * K1 + i] = s2y[i];
    d1z[(size_t)b * K1 + i] = s2z[i];
  }
}

// ---------------- radius + 32 nearest (SoA reads) ----------------
struct RadSmem {
  float candd[4][RCAP];
  int   candi[4][RCAP];
};

__device__ __forceinline__ void radius_body(
    const float* __restrict__ ptsx, const float* __restrict__ ptsy,
    const float* __restrict__ ptsz, int N,
    const float* __restrict__ cxs, const float* __restrict__ cys,
    const float* __restrict__ czs, int K, int CSTR, float r2,
    int* __restrict__ nbr, int* __restrict__ cnt_out, RadSmem& sm, int rb) {
  const int t = threadIdx.x;
  const int lane = t & 63, wave = t >> 6;
  const int bpg = K / 4;
  const int b = rb / bpg;
  const int ci = (rb % bpg) * 4 + wave;
  const size_t pbase = (size_t)b * N;
  const size_t cbase = (size_t)b * CSTR + ci;
  const float cx = cxs[cbase], cy = cys[cbase], cz = czs[cbase];
  int total = 0;
  for (int base = 0; base < N; base += 64) {
    const int p = base + lane;
    const float dx = ptsx[pbase + p] - cx;
    const float dy = ptsy[pbase + p] - cy;
    const float dz = ptsz[pbase + p] - cz;
    const float d2 = dx * dx + dy * dy + dz * dz;
    const bool pred = d2 <= r2;
    const unsigned long long m = __ballot(pred);
    if (pred) {
      const int slot = total + __popcll(m & ((1ull << lane) - 1ull));
      if (slot < RCAP) { sm.candd[wave][slot] = d2; sm.candi[wave][slot] = p; }
    }
    total += __popcll(m);
  }
  if (total > RCAP) total = RCAP;
  int* nbp = nbr + ((size_t)b * K + ci) * MAXN;
  if (total <= MAXN) {
    if (lane < total) nbp[lane] = sm.candi[wave][lane];
  } else {
    for (int jj = 0; jj < MAXN; jj++) {
      float bvd = INFINITY; int bvi = 0x7fffffff; int bslot = 0;
      for (int s = lane; s < total; s += 64) {
        const float d = sm.candd[wave][s];
        const int i = sm.candi[wave][s];
        if (d < bvd || (d == bvd && i < bvi)) { bvd = d; bvi = i; bslot = s; }
      }
#pragma unroll
      for (int off = 32; off; off >>= 1) {
        const float od = __shfl_xor(bvd, off);
        const int   oi = __shfl_xor(bvi, off);
        const int   os = __shfl_xor(bslot, off);
        if (od < bvd || (od == bvd && oi < bvi)) { bvd = od; bvi = oi; bslot = os; }
      }
      if (lane == 0) { nbp[jj] = bvi; sm.candd[wave][bslot] = INFINITY; }
    }
  }
  if (lane == 0) cnt_out[(size_t)b * K + ci] = (total < MAXN) ? total : MAXN;
}

// merged radius1 (blocks 0..NB*K1/4-1) | radius2 (rest)
__global__ __launch_bounds__(256) void rad12_kernel(
    const float* __restrict__ pxg, const float* __restrict__ pyg,
    const float* __restrict__ pzg,
    const float* __restrict__ d1x, const float* __restrict__ d1y,
    const float* __restrict__ d1z,
    int* __restrict__ nbr1, int* __restrict__ cnt1,
    int* __restrict__ nbr2, int* __restrict__ cnt2) {
  constexpr int NR1 = NB * K1 / 4;
  __shared__ __align__(16) RadSmem r;
  if (blockIdx.x < (unsigned)NR1) {
    radius_body(pxg, pyg, pzg, N1, d1x, d1y, d1z, K1, K1, 4.0f,
                nbr1, cnt1, r, blockIdx.x);
  } else {
    radius_body(d1x, d1y, d1z, K1, d1x, d1y, d1z, K2, K1, 16.0f,
                nbr2, cnt2, r, blockIdx.x - NR1);
  }
}

// ---------------- PointNetConv edge MLP + max aggregation ----------------
// Rows-in-lanes + readlane broadcast; vectorized weight streaming (round-11
// form, scalar fmaf -- the pk_fma variant spilled to scratch and regressed).
template<int CIN_T, int H, int COUT, bool SCALE>
__device__ __forceinline__ void sa_conv_body(
    const float* __restrict__ xin,
    const float* __restrict__ ptsx, const float* __restrict__ ptsy,
    const float* __restrict__ ptsz,
    const float* __restrict__ cxs, const float* __restrict__ cys,
    const float* __restrict__ czs,
    const int* __restrict__ nbr, const int* __restrict__ cnt,
    const float* __restrict__ w1, const float* __restrict__ b1,
    const float* __restrict__ w2, const float* __restrict__ b2,
    const float* __restrict__ smean, const float* __restrict__ sstd,
    int N, int K, int CSTR, float* __restrict__ xout,
    float* part /* LDS [4*COUT] */, int bk) {
  constexpr int FIN  = CIN_T + 3;
  constexpr int KREG = (FIN + 63) / 64;   // feat regs per row per lane
  constexpr int HREG = H / 64;            // hidden regs: h = lane*HREG + q
  constexpr int CREG = COUT / 64;         // out regs:    c = lane*CREG + q
  constexpr int RPW  = MAXN / 4;          // 8 rows per wave
  const int t = threadIdx.x, lane = t & 63, wave = t >> 6;
  const int b = bk / K;
  const int V = cnt[bk];
  float m[CREG];
#pragma unroll
  for (int ck = 0; ck < CREG; ck++) m[ck] = -INFINITY;
  if (V > wave * RPW) {  // wave-uniform: skip waves with no valid rows
    const int* nb = nbr + (size_t)bk * MAXN;
    const size_t crow = (size_t)b * CSTR + (bk - b * K);
    const float ctrx = cxs[crow];
    const float ctry = cys[crow];
    const float ctrz = czs[crow];
    float sm = 0.0f, sd = 1.0f;
    if (SCALE && lane < CIN_T) { sm = smean[lane]; sd = sstd[lane]; }
    float fr[RPW][KREG];
#pragma unroll
    for (int r = 0; r < RPW; r++) {
      const int j = wave * RPW + r;
      const int p = (j < V) ? nb[j] : nb[0];
#pragma unroll
      for (int k2 = 0; k2 < KREG; k2++) {
        const int f = k2 * 64 + lane;
        float v = 0.0f;
        if (f < CIN_T) {
          v = xin[((size_t)b * N + p) * CIN_T + f];
          if constexpr (SCALE) v = (v - sm) / sd;
        } else if (f < FIN) {
          const int d = f - CIN_T;
          const float pv = (d == 0 ? ptsx : (d == 1 ? ptsy : ptsz))[(size_t)b * N + p];
          v = pv - (d == 0 ? ctrx : (d == 1 ? ctry : ctrz));
        }
        fr[r][k2] = v;
      }
    }
    // ---- layer 1 ----
    float hh[RPW][HREG];
    {
      float acc[RPW][HREG];
#pragma unroll
      for (int r = 0; r < RPW; r++)
#pragma unroll
        for (int q = 0; q < HREG; q++) acc[r][q] = 0.0f;
#pragma unroll
      for (int k2 = 0; k2 < KREG; k2++) {
        const int lim = (FIN - k2 * 64) < 64 ? (FIN - k2 * 64) : 64;
        for (int fl = 0; fl < lim; fl++) {     // f ascending
          const int f = k2 * 64 + fl;
          float wv[HREG];
          if constexpr (HREG == 1) {
            wv[0] = w1[(size_t)f * H + lane];
          } else {
            const float2 w = *reinterpret_cast<const float2*>(
                &w1[(size_t)f * H + lane * 2]);
            wv[0] = w.x; wv[1] = w.y;
          }
#pragma unroll
          for (int r = 0; r < RPW; r++) {
            const float s = readlane_f(fr[r][k2], fl);
#pragma unroll
            for (int q = 0; q < HREG; q++) acc[r][q] = fmaf(s, wv[q], acc[r][q]);
          }
        }
      }
#pragma unroll
      for (int q = 0; q < HREG; q++) {
        const float bb = b1[lane * HREG + q];
#pragma unroll
        for (int r = 0; r < RPW; r++) hh[r][q] = sigmoidf_(acc[r][q] + bb);
      }
    }
    // ---- layer 2 (h = hl*HREG + q1 enumerated ascending) ----
    float acc2[RPW][CREG];
#pragma unroll
    for (int r = 0; r < RPW; r++)
#pragma unroll
      for (int q = 0; q < CREG; q++) acc2[r][q] = 0.0f;
    for (int hl = 0; hl < 64; hl++) {
#pragma unroll
      for (int q1 = 0; q1 < HREG; q1++) {
        const int h = hl * HREG + q1;
        float wv[CREG];
        if constexpr (CREG == 2) {
          const float2 w = *reinterpret_cast<const float2*>(
              &w2[(size_t)h * COUT + lane * 2]);
          wv[0] = w.x; wv[1] = w.y;
        } else {
          const float4 w = *reinterpret_cast<const float4*>(
              &w2[(size_t)h * COUT + lane * 4]);
          wv[0] = w.x; wv[1] = w.y; wv[2] = w.z; wv[3] = w.w;
        }
#pragma unroll
        for (int r = 0; r < RPW; r++) {
          const float s = readlane_f(hh[r][q1], hl);
#pragma unroll
          for (int q = 0; q < CREG; q++) acc2[r][q] = fmaf(s, wv[q], acc2[r][q]);
        }
      }
    }
#pragma unroll
    for (int r = 0; r < RPW; r++) {
      if (wave * RPW + r < V) {
#pragma unroll
        for (int q = 0; q < CREG; q++) m[q] = fmaxf(m[q], acc2[r][q]);
      }
    }
  }
#pragma unroll
  for (int q = 0; q < CREG; q++) part[wave * COUT + lane * CREG + q] = m[q];
  __syncthreads();
  if (t < COUT) {
    const float mm = fmaxf(fmaxf(part[0 * COUT + t], part[1 * COUT + t]),
                           fmaxf(part[2 * COUT + t], part[3 * COUT + t]));
    const float o = mm + b2[t];
    xout[(size_t)bk * COUT + t] = o > 0.0f ? o : 0.0f;
  }
}

__global__ __launch_bounds__(256) void conv1_kernel(
    const float* __restrict__ x,
    const float* __restrict__ pxg, const float* __restrict__ pyg,
    const float* __restrict__ pzg,
    const float* __restrict__ d1x, const float* __restrict__ d1y,
    const float* __restrict__ d1z,
    const int* __restrict__ nbr1, const int* __restrict__ cnt1,
    const float* __restrict__ s1w1, const float* __restrict__ s1b1,
    const float* __restrict__ s1w2, const float* __restrict__ s1b2,
    const float* __restrict__ smean, const float* __restrict__ sstd,
    float* __restrict__ x1) {
  __shared__ __align__(16) float part[4 * 128];
  sa_conv_body<32, 64, 128, true>(x, pxg, pyg, pzg, d1x, d1y, d1z,
                                  nbr1, cnt1, s1w1, s1b1, s1w2, s1b2,
                                  smean, sstd, N1, K1, K1, x1, part,
                                  blockIdx.x);
}

__global__ __launch_bounds__(256) void conv2_kernel(
    const float* __restrict__ x1,
    const float* __restrict__ d1x, const float* __restrict__ d1y,
    const float* __restrict__ d1z,
    const int* __restrict__ nbr2, const int* __restrict__ cnt2,
    const float* __restrict__ s2w1, const float* __restrict__ s2b1,
    const float* __restrict__ s2w2, const float* __restrict__ s2b2,
    float* __restrict__ x2) {
  __shared__ __align__(16) float part[4 * 256];
  // points AND centers = posd1 (centers are its first K2 rows per graph)
  sa_conv_body<128, 128, 256, false>(x1, d1x, d1y, d1z, d1x, d1y, d1z,
                                     nbr2, cnt2, s2w1, s2b1, s2w2, s2b2,
                                     nullptr, nullptr, K1, K2, K1, x2, part,
                                     blockIdx.x);
}

// ---------------- Global SA: MLP(259->256->512) + relu + max pool ----------
__global__ __launch_bounds__(256) void global_sa_kernel(
    const float* __restrict__ x2,
    const float* __restrict__ d1x, const float* __restrict__ d1y,
    const float* __restrict__ d1z,
    const float* __restrict__ gw1, const float* __restrict__ gb1,
    const float* __restrict__ gw2, const float* __restrict__ gb2,
    unsigned int* __restrict__ gout) {  // [B][512] as float bits (relu >= 0)
  __shared__ float fin[4][259];
  __shared__ float s[4][256];
  const int t = threadIdx.x;
  const int blk = blockIdx.x;
  const int b = blk / 64;
  const int p0 = (blk % 64) * 4;
  for (int item = t; item < 4 * 259; item += 256) {
    const int p = item / 259, f = item - p * 259;
    float v;
    if (f < 256) {
      v = x2[((size_t)b * 256 + p0 + p) * 256 + f];
    } else {
      const int d = f - 256;
      v = (d == 0 ? d1x : (d == 1 ? d1y : d1z))[(size_t)b * K1 + p0 + p];
    }
    fin[p][f] = v;
  }
  __syncthreads();
  float acc[4] = {0.f, 0.f, 0.f, 0.f};
  for (int f = 0; f < 259; f++) {
    const float w = gw1[f * 256 + t];
#pragma unroll
    for (int p = 0; p < 4; p++) acc[p] = fmaf(fin[p][f], w, acc[p]);
  }
  const float bb = gb1[t];
#pragma unroll
  for (int p = 0; p < 4; p++) s[p][t] = sigmoidf_(acc[p] + bb);
  __syncthreads();
  float a0[4] = {0.f, 0.f, 0.f, 0.f}, a1[4] = {0.f, 0.f, 0.f, 0.f};
  for (int h = 0; h < 256; h++) {
    const float w0 = gw2[h * 512 + t];
    const float w1v = gw2[h * 512 + t + 256];
#pragma unroll
    for (int p = 0; p < 4; p++) {
      a0[p] = fmaf(s[p][h], w0, a0[p]);
      a1[p] = fmaf(s[p][h], w1v, a1[p]);
    }
  }
  const float b0 = gb2[t], b1v = gb2[t + 256];
  float m0 = 0.0f, m1 = 0.0f;  // relu floor
#pragma unroll
  for (int p = 0; p < 4; p++) {
    m0 = fmaxf(m0, fmaxf(a0[p] + b0, 0.0f));
    m1 = fmaxf(m1, fmaxf(a1[p] + b1v, 0.0f));
  }
  atomicMax(&gout[b * 512 + t], __float_as_uint(m0));
  atomicMax(&gout[b * 512 + t + 256], __float_as_uint(m1));
}

// ---------------- Final FC head (float32 output) ----------------
__global__ __launch_bounds__(256) void fc_kernel(
    const unsigned int* __restrict__ g,
    const float* __restrict__ fw1, const float* __restrict__ fb1,
    const float* __restrict__ fw2, const float* __restrict__ fb2,
    float* __restrict__ out) {
  __shared__ float gv[512];
  __shared__ float s[256];
  const int b = blockIdx.x, t = threadIdx.x;
  gv[t] = __uint_as_float(g[b * 512 + t]);
  gv[t + 256] = __uint_as_float(g[b * 512 + t + 256]);
  __syncthreads();
  float acc = 0.0f;
  for (int h = 0; h < 512; h++) acc = fmaf(gv[h], fw1[h * 256 + t], acc);
  s[t] = sigmoidf_(acc + fb1[t]);
  __syncthreads();
  if (t < 128) {
    float a2 = 0.0f;
    for (int h = 0; h < 256; h++) a2 = fmaf(s[h], fw2[h * 128 + t], a2);
    const float o = a2 + fb2[t];
    out[b * 128 + t] = o > 0.0f ? o : 0.0f;
  }
}

}  // namespace

extern "C" void kernel_launch(void* const* d_in, const int* in_sizes, int n_in,
                              void* d_out, int out_size, void* d_ws, size_t ws_size,
                              hipStream_t stream) {
  (void)in_sizes; (void)n_in; (void)out_size; (void)ws_size;
  const float* x     = (const float*)d_in[0];
  const float* pos   = (const float*)d_in[1];
  // d_in[2] = batch (int64) — sorted, equal-sized graphs, unused
  const float* smean = (const float*)d_in[3];
  const float* sstd  = (const float*)d_in[4];
  const float* s1w1  = (const float*)d_in[5];
  const float* s1b1  = (const float*)d_in[6];
  const float* s1w2  = (const float*)d_in[7];
  const float* s1b2  = (const float*)d_in[8];
  const float* s2w1  = (const float*)d_in[9];
  const float* s2b1  = (const float*)d_in[10];
  const float* s2w2  = (const float*)d_in[11];
  const float* s2b2  = (const float*)d_in[12];
  const float* gw1   = (const float*)d_in[13];
  const float* gb1   = (const float*)d_in[14];
  const float* gw2   = (const float*)d_in[15];
  const float* gb2   = (const float*)d_in[16];
  const float* fw1   = (const float*)d_in[17];
  const float* fb1   = (const float*)d_in[18];
  const float* fw2   = (const float*)d_in[19];
  const float* fb2   = (const float*)d_in[20];

  char* ws = (char*)d_ws;
  size_t off = 0;
  auto take = [&](size_t bytes) -> char* {
    char* p = ws + off;
    off = (off + bytes + 255) & ~(size_t)255;
    return p;
  };
  float* pxg         = (float*)take((size_t)NB * N1 * 4);
  float* pyg         = (float*)take((size_t)NB * N1 * 4);
  float* pzg         = (float*)take((size_t)NB * N1 * 4);
  float* d1x         = (float*)take((size_t)NB * K1 * 4);
  float* d1y         = (float*)take((size_t)NB * K1 * 4);
  float* d1z         = (float*)take((size_t)NB * K1 * 4);
  int*   nbr1        = (int*)take((size_t)NB * K1 * MAXN * 4);
  int*   cnt1        = (int*)take((size_t)NB * K1 * 4);
  float* x1          = (float*)take((size_t)NB * K1 * 128 * 4);
  int*   nbr2        = (int*)take((size_t)NB * K2 * MAXN * 4);
  int*   cnt2        = (int*)take((size_t)NB * K2 * 4);
  float* x2          = (float*)take((size_t)NB * K2 * 256 * 4);
  unsigned int* gbuf = (unsigned int*)take((size_t)NB * 512 * 4);

  hipLaunchKernelGGL(fps_l1_kernel, dim3(NB), dim3(256), 0, stream,
                     pos, pxg, pyg, pzg, d1x, d1y, d1z, gbuf);
  hipLaunchKernelGGL(rad12_kernel, dim3(NB * K1 / 4 + NB * K2 / 4), dim3(256), 0, stream,
                     pxg, pyg, pzg, d1x, d1y, d1z, nbr1, cnt1, nbr2, cnt2);
  hipLaunchKernelGGL(conv1_kernel, dim3(NB * K1), dim3(256), 0, stream,
                     x, pxg, pyg, pzg, d1x, d1y, d1z, nbr1, cnt1,
                     s1w1, s1b1, s1w2, s1b2, smean, sstd, x1);
  hipLaunchKernelGGL(conv2_kernel, dim3(NB * K2), dim3(256), 0, stream,
                     x1, d1x, d1y, d1z, nbr2, cnt2,
                     s2w1, s2b1, s2w2, s2b2, x2);
  hipLaunchKernelGGL(global_sa_kernel, dim3(NB * 64), dim3(256), 0, stream,
                     x2, d1x, d1y, d1z, gw1, gb1, gw2, gb2, gbuf);
  hipLaunchKernelGGL(fc_kernel, dim3(NB), dim3(256), 0, stream,
                     gbuf, fw1, fb1, fw2, fb2, (float*)d_out);
}